// Round 9
// baseline (441.273 us; speedup 1.0000x reference)
//
#include <hip/hip_runtime.h>
#include <math.h>

constexpr int KIN = 128;   // IN_F

typedef _Float16 half8_t __attribute__((ext_vector_type(8)));
typedef _Float16 half4_t __attribute__((ext_vector_type(4)));

// ---------------- graph build: MSD bucket sort (dst>>9), then per-bucket
// counting sort by dst&511. NB=512 chunks (rx_* were occupancy-starved at 128). --

__global__ void rx_hist(const int* __restrict__ dst, int* __restrict__ hist_g,
                        int E, int CH, int NB, int NBKT) {
    __shared__ int h[256];
    int b = blockIdx.x;
    for (int i = threadIdx.x; i < 256; i += blockDim.x) h[i] = 0;
    __syncthreads();
    int beg = b * CH, end = min(beg + CH, E);
    for (int e = beg + threadIdx.x; e < end; e += blockDim.x)
        atomicAdd(&h[dst[e] >> 9], 1);
    __syncthreads();
    for (int d = threadIdx.x; d < NBKT; d += blockDim.x)
        hist_g[d * NB + b] = h[d];
}

__global__ void gs_reduce(const int* __restrict__ a, int* __restrict__ bsum, int m) {
    __shared__ int s[256];
    int t = threadIdx.x;
    int i = blockIdx.x * 256 + t;
    s[t] = (i < m) ? a[i] : 0;
    __syncthreads();
    for (int off = 128; off > 0; off >>= 1) {
        if (t < off) s[t] += s[t + off];
        __syncthreads();
    }
    if (t == 0) bsum[blockIdx.x] = s[0];
}

__global__ void gs_blocksums(const int* __restrict__ bsum, int* __restrict__ bpre, int nb) {
    __shared__ int s[512];
    int t = threadIdx.x;
    int val = (t < nb) ? bsum[t] : 0;
    s[t] = val;
    __syncthreads();
    for (int off = 1; off < 512; off <<= 1) {
        int x = (t >= off) ? s[t - off] : 0;
        __syncthreads();
        s[t] += x;
        __syncthreads();
    }
    if (t < nb) bpre[t] = s[t] - val;  // exclusive
}

__global__ void gs_scatter(const int* __restrict__ a, const int* __restrict__ bpre,
                           int* __restrict__ out, int m) {
    __shared__ int s[256];
    int t = threadIdx.x;
    int i = blockIdx.x * 256 + t;
    int val = (i < m) ? a[i] : 0;
    s[t] = val;
    __syncthreads();
    for (int off = 1; off < 256; off <<= 1) {
        int x = (t >= off) ? s[t - off] : 0;
        __syncthreads();
        s[t] += x;
        __syncthreads();
    }
    if (i < m) out[i] = bpre[blockIdx.x] + s[t] - val;
}

__global__ void rx_scatter(const int* __restrict__ src, const int* __restrict__ dst,
                           const int* __restrict__ excl, int* __restrict__ s1,
                           int* __restrict__ d1, int E, int CH, int NB, int NBKT) {
    __shared__ int offs[256];
    int b = blockIdx.x;
    for (int d = threadIdx.x; d < NBKT; d += blockDim.x)
        offs[d] = excl[d * NB + b];
    __syncthreads();
    int beg = b * CH, end = min(beg + CH, E);
    for (int e = beg + threadIdx.x; e < end; e += blockDim.x) {
        int dd = dst[e];
        int pos = atomicAdd(&offs[dd >> 9], 1);
        s1[pos] = src[e];
        d1[pos] = dd;
    }
}

__global__ void __launch_bounds__(512)
bucket_sort(const int* __restrict__ s1, const int* __restrict__ d1,
            const int* __restrict__ excl, int* __restrict__ csr,
            int* __restrict__ row_ptr, float* __restrict__ dinv,
            int E, int NB, int NBKT, int n) {
    __shared__ int hist[512];
    __shared__ int scan[512];
    __shared__ int offs[512];
    int b = blockIdx.x, t = threadIdx.x;
    int base = excl[b * NB];
    int endb = (b + 1 < NBKT) ? excl[(b + 1) * NB] : E;
    hist[t] = 0;
    __syncthreads();
    for (int i = base + t; i < endb; i += 512)
        atomicAdd(&hist[d1[i] & 511], 1);
    __syncthreads();
    int v = hist[t];
    scan[t] = v;
    __syncthreads();
    for (int off = 1; off < 512; off <<= 1) {
        int x = (t >= off) ? scan[t - off] : 0;
        __syncthreads();
        scan[t] += x;
        __syncthreads();
    }
    int ex = scan[t] - v;  // exclusive prefix within bucket
    offs[t] = ex;
    int node = b * 512 + t;
    if (node < n) {
        row_ptr[node] = base + ex;
        dinv[node] = 1.0f / sqrtf((float)(v + 1));  // +1 self loop
    }
    if (b == NBKT - 1 && t == 0) row_ptr[n] = E;
    __syncthreads();
    for (int i = base + t; i < endb; i += 512) {
        int dd = d1[i];
        int pos = atomicAdd(&offs[dd & 511], 1);
        csr[base + pos] = s1[i];
    }
}

// ---------------- tiled register-blocked GEMM ----------------
template <int K, int F, int BM, int THREADS, bool SCALE, bool BRELU, bool ATT, bool OUT16>
__global__ void __launch_bounds__(THREADS)
gemm_tile(const float* __restrict__ in, const float* __restrict__ W,
          const float* __restrict__ dinv, const float* __restrict__ bias,
          const float* __restrict__ att_src, const float* __restrict__ att_dst,
          float* __restrict__ a_s, float* __restrict__ a_d,
          float* __restrict__ out, int n) {
    constexpr int TM = 4, TN = 4;
    constexpr int TX = F / TN;
    constexpr int TY = BM / TM;
    static_assert(THREADS == TX * TY, "thread count mismatch");
    constexpr int K4 = K / 4;
    __shared__ float xs[K][BM];
    __shared__ float Ws[K * F];
    int t = threadIdx.x;
    int row0 = blockIdx.x * BM;

    for (int i = t; i < K * F / 4; i += THREADS)
        ((float4*)Ws)[i] = ((const float4*)W)[i];

    for (int i = t; i < BM * K4; i += THREADS) {
        int r = i % BM, k4 = i / BM;
        int row = row0 + r;
        float4 v = {0.f, 0.f, 0.f, 0.f};
        if (row < n) v = ((const float4*)(in + (size_t)row * K))[k4];
        xs[4 * k4 + 0][r] = v.x;
        xs[4 * k4 + 1][r] = v.y;
        xs[4 * k4 + 2][r] = v.z;
        xs[4 * k4 + 3][r] = v.w;
    }
    __syncthreads();

    int tx = t % TX, ty = t / TX;
    float acc[TM][TN] = {};
#pragma unroll 4
    for (int k = 0; k < K; ++k) {
        float4 xv = *(const float4*)&xs[k][ty * TM];
        float4 wv = *(const float4*)&Ws[k * F + tx * TN];
        float xr[4] = {xv.x, xv.y, xv.z, xv.w};
        float wr[4] = {wv.x, wv.y, wv.z, wv.w};
#pragma unroll
        for (int i = 0; i < TM; ++i)
#pragma unroll
            for (int j = 0; j < TN; ++j)
                acc[i][j] = fmaf(xr[i], wr[j], acc[i][j]);
    }

#pragma unroll
    for (int i = 0; i < TM; ++i) {
        int row = row0 + ty * TM + i;
        if (row >= n) continue;
        float s = SCALE ? dinv[row] : 1.0f;
        float o[4];
        if (BRELU) {
            o[0] = fmaxf(fmaf(acc[i][0], s, bias[4 * tx + 0]), 0.f);
            o[1] = fmaxf(fmaf(acc[i][1], s, bias[4 * tx + 1]), 0.f);
            o[2] = fmaxf(fmaf(acc[i][2], s, bias[4 * tx + 2]), 0.f);
            o[3] = fmaxf(fmaf(acc[i][3], s, bias[4 * tx + 3]), 0.f);
        } else {
            o[0] = acc[i][0] * s; o[1] = acc[i][1] * s;
            o[2] = acc[i][2] * s; o[3] = acc[i][3] * s;
        }
        if (OUT16) {
            half4_t oh;
            oh[0] = (_Float16)o[0]; oh[1] = (_Float16)o[1];
            oh[2] = (_Float16)o[2]; oh[3] = (_Float16)o[3];
            *(half4_t*)((_Float16*)out + (size_t)row * F + 4 * tx) = oh;
        } else {
            float4 of = {o[0], o[1], o[2], o[3]};
            ((float4*)(out + (size_t)row * F))[tx] = of;
        }
    }
    if (ATT) {
        int hd = tx >> 2;
        float as0 = att_src[4 * tx + 0], as1 = att_src[4 * tx + 1];
        float as2 = att_src[4 * tx + 2], as3 = att_src[4 * tx + 3];
        float ad0 = att_dst[4 * tx + 0], ad1 = att_dst[4 * tx + 1];
        float ad2 = att_dst[4 * tx + 2], ad3 = att_dst[4 * tx + 3];
#pragma unroll
        for (int i = 0; i < TM; ++i) {
            float ps = acc[i][0] * as0 + acc[i][1] * as1 + acc[i][2] * as2 + acc[i][3] * as3;
            float pd = acc[i][0] * ad0 + acc[i][1] * ad1 + acc[i][2] * ad2 + acc[i][3] * ad3;
            ps += __shfl_xor(ps, 1); pd += __shfl_xor(pd, 1);
            ps += __shfl_xor(ps, 2); pd += __shfl_xor(pd, 2);
            int row = row0 + ty * TM + i;
            if ((tx & 3) == 0 && row < n) {
                a_s[row * 4 + hd] = ps;
                a_d[row * 4 + hd] = pd;
            }
        }
    }
}

// ---------------- fused layer2-GEMM + GAT1-GEMM (A1 stored fp16) ----------------
__global__ void __launch_bounds__(256)
gemm2_gat(const float* __restrict__ T, const float* __restrict__ W2,
          const float* __restrict__ b2, const float* __restrict__ dinv,
          const float* __restrict__ Wg, const float* __restrict__ att_src,
          const float* __restrict__ att_dst, float* __restrict__ a_s,
          float* __restrict__ a_d, float* __restrict__ A1, int n) {
    __shared__ float xs[32][64];
    __shared__ float W2s[32 * 64];
    __shared__ float Wgs[64 * 64];
    __shared__ float hs[64][68];
    int t = threadIdx.x;
    int row0 = blockIdx.x * 64;

    for (int i = t; i < 32 * 64 / 4; i += 256) ((float4*)W2s)[i] = ((const float4*)W2)[i];
    for (int i = t; i < 64 * 64 / 4; i += 256) ((float4*)Wgs)[i] = ((const float4*)Wg)[i];
    for (int i = t; i < 64 * 8; i += 256) {
        int r = i % 64, k4 = i / 64;
        int row = row0 + r;
        float4 v = {0.f, 0.f, 0.f, 0.f};
        if (row < n) v = ((const float4*)(T + (size_t)row * 32))[k4];
        xs[4 * k4 + 0][r] = v.x;
        xs[4 * k4 + 1][r] = v.y;
        xs[4 * k4 + 2][r] = v.z;
        xs[4 * k4 + 3][r] = v.w;
    }
    __syncthreads();

    int tx = t % 16, ty = t / 16;
    {
        float acc[4][4] = {};
#pragma unroll 4
        for (int k = 0; k < 32; ++k) {
            float4 xv = *(const float4*)&xs[k][ty * 4];
            float4 wv = *(const float4*)&W2s[k * 64 + tx * 4];
            float xr[4] = {xv.x, xv.y, xv.z, xv.w};
            float wr[4] = {wv.x, wv.y, wv.z, wv.w};
#pragma unroll
            for (int i = 0; i < 4; ++i)
#pragma unroll
                for (int j = 0; j < 4; ++j)
                    acc[i][j] = fmaf(xr[i], wr[j], acc[i][j]);
        }
#pragma unroll
        for (int i = 0; i < 4; ++i) {
            int row = row0 + ty * 4 + i;
            float s = (row < n) ? dinv[row] : 0.f;
#pragma unroll
            for (int j = 0; j < 4; ++j)
                hs[4 * tx + j][ty * 4 + i] = fmaxf(fmaf(acc[i][j], s, b2[4 * tx + j]), 0.f);
        }
    }
    __syncthreads();

    float acc[4][4] = {};
#pragma unroll 4
    for (int k = 0; k < 64; ++k) {
        float4 xv = *(const float4*)&hs[k][ty * 4];
        float4 wv = *(const float4*)&Wgs[k * 64 + tx * 4];
        float xr[4] = {xv.x, xv.y, xv.z, xv.w};
        float wr[4] = {wv.x, wv.y, wv.z, wv.w};
#pragma unroll
        for (int i = 0; i < 4; ++i)
#pragma unroll
            for (int j = 0; j < 4; ++j)
                acc[i][j] = fmaf(xr[i], wr[j], acc[i][j]);
    }
    _Float16* A1h = (_Float16*)A1;
#pragma unroll
    for (int i = 0; i < 4; ++i) {
        int row = row0 + ty * 4 + i;
        if (row >= n) continue;
        half4_t oh;
        oh[0] = (_Float16)acc[i][0]; oh[1] = (_Float16)acc[i][1];
        oh[2] = (_Float16)acc[i][2]; oh[3] = (_Float16)acc[i][3];
        *(half4_t*)(A1h + (size_t)row * 64 + 4 * tx) = oh;
    }
    {
        int hd = tx >> 2;
        float as0 = att_src[4 * tx + 0], as1 = att_src[4 * tx + 1];
        float as2 = att_src[4 * tx + 2], as3 = att_src[4 * tx + 3];
        float ad0 = att_dst[4 * tx + 0], ad1 = att_dst[4 * tx + 1];
        float ad2 = att_dst[4 * tx + 2], ad3 = att_dst[4 * tx + 3];
#pragma unroll
        for (int i = 0; i < 4; ++i) {
            float ps = acc[i][0] * as0 + acc[i][1] * as1 + acc[i][2] * as2 + acc[i][3] * as3;
            float pd = acc[i][0] * ad0 + acc[i][1] * ad1 + acc[i][2] * ad2 + acc[i][3] * ad3;
            ps += __shfl_xor(ps, 1); pd += __shfl_xor(pd, 1);
            ps += __shfl_xor(ps, 2); pd += __shfl_xor(pd, 2);
            int row = row0 + ty * 4 + i;
            if ((tx & 3) == 0 && row < n) {
                a_s[row * 4 + hd] = ps;
                a_d[row * 4 + hd] = pd;
            }
        }
    }
}

// ---------------- aggregation kernels: 2 nodes/wave, 2-deep A/B pipeline ----------
// Unroll-2 body: process A; load A<-i+2; process B; load B<-i+3. Each stage's
// registers written once per body -> no v_mov copies (round-5 mistake), but 2
// gathers stay in flight per wave (latency cover at VALU ~48%).

// fp16-gather GCN agg, 32-wide rows (64B). Per half: 4 cg-lanes x 8 slots.
// MODE 1: out[fp16] = dinv*relu(dinv*acc + b)   MODE 2: out[f32] = acc
template <int MODE>
__global__ void __launch_bounds__(256)
gcn_agg_h32(const _Float16* __restrict__ Hs, const int* __restrict__ row_ptr,
            const int* __restrict__ csr, const float* __restrict__ dinv,
            const float* __restrict__ bias, void* __restrict__ outp, int n) {
    int idx = blockIdx.x * blockDim.x + threadIdx.x;
    int wave = idx >> 6;
    int lane = idx & 63;
    int half = lane >> 5;
    int l32 = lane & 31;
    int v = (wave << 1) + half;
    bool vok = v < n;
    int vc = vok ? v : 0;
    int cg = l32 & 3;     // 8 halves per lane
    int slot = l32 >> 2;  // 8 edge slots
    const half8_t* H8 = (const half8_t*)Hs;  // row stride = 4 half8

    float acc[8] = {};
    if (slot == 0 && vok) {  // self loop
        half8_t h = H8[(size_t)vc * 4 + cg];
#pragma unroll
        for (int j = 0; j < 8; ++j) acc[j] = (float)h[j];
    }
    int beg = row_ptr[vc];
    int end = vok ? row_ptr[vc + 1] : beg;
    int iters = (end - beg + 7) >> 3;
    int iters2 = (iters + 1) & ~1;
    int e = beg + slot;
    bool vA = e < end;
    int uA = vA ? csr[e] : vc;
    half8_t hA = H8[(size_t)uA * 4 + cg];
    int eB = e + 8;
    bool vB = eB < end;
    int uB = vB ? csr[eB] : vc;
    half8_t hB = H8[(size_t)uB * 4 + cg];
    int en = e + 16;
    for (int i = 0; i < iters2; i += 2) {
        {  // process A (iter i)
            float m = vA ? 1.f : 0.f;
#pragma unroll
            for (int j = 0; j < 8; ++j) acc[j] = fmaf(m, (float)hA[j], acc[j]);
        }
        {  // load A <- iter i+2
            bool nv = en < end;
            int nu = nv ? csr[en] : vc;
            hA = H8[(size_t)nu * 4 + cg];
            vA = nv; en += 8;
        }
        {  // process B (iter i+1)
            float m = vB ? 1.f : 0.f;
#pragma unroll
            for (int j = 0; j < 8; ++j) acc[j] = fmaf(m, (float)hB[j], acc[j]);
        }
        {  // load B <- iter i+3
            bool nv = en < end;
            int nu = nv ? csr[en] : vc;
            hB = H8[(size_t)nu * 4 + cg];
            vB = nv; en += 8;
        }
    }
    // reduce over slots (bits 2,3,4 of l32 -> offsets 4,8,16; stays in half)
#pragma unroll
    for (int off = 4; off < 32; off <<= 1) {
#pragma unroll
        for (int j = 0; j < 8; ++j) acc[j] += __shfl_xor(acc[j], off);
    }
    if (slot == 0 && vok) {
        if (MODE == 1) {
            float dv = dinv[vc];
            half8_t o;
#pragma unroll
            for (int j = 0; j < 8; ++j)
                o[j] = (_Float16)(dv * fmaxf(fmaf(dv, acc[j], bias[8 * cg + j]), 0.f));
            ((half8_t*)outp)[(size_t)vc * 4 + cg] = o;
        } else {
            float* of = (float*)outp;
            float4 o0 = {acc[0], acc[1], acc[2], acc[3]};
            float4 o1 = {acc[4], acc[5], acc[6], acc[7]};
            float4* dst4 = (float4*)(of + (size_t)vc * 32 + 8 * cg);
            dst4[0] = o0;
            dst4[1] = o1;
        }
    }
}

// fp16-gather GCN agg, F=64, relu+bias+residual, f32 out. Per half: 8 cg x 4 slots.
__global__ void __launch_bounds__(256)
gcn_agg_h64(const _Float16* __restrict__ Hs, const int* __restrict__ row_ptr,
            const int* __restrict__ csr, const float* __restrict__ dinv,
            const float* __restrict__ bias, const float* __restrict__ res,
            float* __restrict__ out, int n) {
    int idx = blockIdx.x * blockDim.x + threadIdx.x;
    int wave = idx >> 6;
    int lane = idx & 63;
    int half = lane >> 5;
    int l32 = lane & 31;
    int v = (wave << 1) + half;
    bool vok = v < n;
    int vc = vok ? v : 0;
    int cg = l32 & 7;     // 8 halves per lane
    int slot = l32 >> 3;  // 4 edge slots
    const half8_t* H8 = (const half8_t*)Hs;

    float acc[8] = {};
    if (slot == 0 && vok) {  // self loop
        half8_t h = H8[(size_t)vc * 8 + cg];
#pragma unroll
        for (int j = 0; j < 8; ++j) acc[j] = (float)h[j];
    }
    int beg = row_ptr[vc];
    int end = vok ? row_ptr[vc + 1] : beg;
    int iters = (end - beg + 3) >> 2;
    int iters2 = (iters + 1) & ~1;
    int e = beg + slot;
    bool vA = e < end;
    int uA = vA ? csr[e] : vc;
    half8_t hA = H8[(size_t)uA * 8 + cg];
    int eB = e + 4;
    bool vB = eB < end;
    int uB = vB ? csr[eB] : vc;
    half8_t hB = H8[(size_t)uB * 8 + cg];
    int en = e + 8;
    for (int i = 0; i < iters2; i += 2) {
        {  // process A
            float m = vA ? 1.f : 0.f;
#pragma unroll
            for (int j = 0; j < 8; ++j) acc[j] = fmaf(m, (float)hA[j], acc[j]);
        }
        {  // load A <- i+2
            bool nv = en < end;
            int nu = nv ? csr[en] : vc;
            hA = H8[(size_t)nu * 8 + cg];
            vA = nv; en += 4;
        }
        {  // process B
            float m = vB ? 1.f : 0.f;
#pragma unroll
            for (int j = 0; j < 8; ++j) acc[j] = fmaf(m, (float)hB[j], acc[j]);
        }
        {  // load B <- i+3
            bool nv = en < end;
            int nu = nv ? csr[en] : vc;
            hB = H8[(size_t)nu * 8 + cg];
            vB = nv; en += 4;
        }
    }
    // reduce over slots (bits 3,4 of l32 -> offsets 8,16; stays in half)
#pragma unroll
    for (int off = 8; off < 32; off <<= 1) {
#pragma unroll
        for (int j = 0; j < 8; ++j) acc[j] += __shfl_xor(acc[j], off);
    }
    if (slot == 0 && vok) {
        float dv = dinv[vc];
        const float4* r4 = (const float4*)(res + (size_t)vc * 64 + 8 * cg);
        float4 r0 = r4[0], r1 = r4[1];
        float o[8];
#pragma unroll
        for (int j = 0; j < 8; ++j)
            o[j] = fmaxf(fmaf(dv, acc[j], bias[8 * cg + j]), 0.f);
        float4 o0 = {o[0] + r0.x, o[1] + r0.y, o[2] + r0.z, o[3] + r0.w};
        float4 o1 = {o[4] + r1.x, o[5] + r1.y, o[6] + r1.z, o[7] + r1.w};
        float4* dst4 = (float4*)(out + (size_t)vc * 64 + 8 * cg);
        dst4[0] = o0;
        dst4[1] = o1;
    }
}

// fp16-gather GAT agg. Per half: 8 cg-lanes x 4 slots, 2-deep A/B pipeline.
template <bool FINAL>
__global__ void __launch_bounds__(256)
gat_agg_h(const _Float16* __restrict__ H, const int* __restrict__ row_ptr,
          const int* __restrict__ csr, const float* __restrict__ a_s,
          const float* __restrict__ a_d, const float* __restrict__ bias,
          const float* __restrict__ Wl, const float* __restrict__ bl,
          float* __restrict__ out, int n) {
    int idx = blockIdx.x * blockDim.x + threadIdx.x;
    int wave = idx >> 6;
    int lane = idx & 63;
    int half = lane >> 5;
    int l32 = lane & 31;
    int v = (wave << 1) + half;
    bool vok = v < n;
    int vc = vok ? v : 0;
    int cg = l32 & 7;     // 8 halves (one head-half) per lane
    int slot = l32 >> 3;  // 4 edge slots
    int hd = cg >> 1;
    const half8_t* H8 = (const half8_t*)H;

    float adv = a_d[vc * 4 + hd];
    float l = 0.f;
    float acc[8] = {};
    if (slot == 0 && vok) {  // self edge
        float e0 = a_s[vc * 4 + hd] + adv;
        e0 = fmaxf(e0, 0.2f * e0);
        float p = __expf(e0);
        l = p;
        half8_t h = H8[(size_t)vc * 8 + cg];
#pragma unroll
        for (int j = 0; j < 8; ++j) acc[j] = p * (float)h[j];
    }
    int beg = row_ptr[vc];
    int end = vok ? row_ptr[vc + 1] : beg;
    int iters = (end - beg + 3) >> 2;
    int iters2 = (iters + 1) & ~1;
    int e = beg + slot;
    bool vA = e < end;
    int uA = vA ? csr[e] : vc;
    half8_t hA = H8[(size_t)uA * 8 + cg];
    float asA = a_s[uA * 4 + hd];
    int eB = e + 4;
    bool vB = eB < end;
    int uB = vB ? csr[eB] : vc;
    half8_t hB = H8[(size_t)uB * 8 + cg];
    float asB = a_s[uB * 4 + hd];
    int en = e + 8;
    for (int i = 0; i < iters2; i += 2) {
        {  // process A (iter i)
            float ev = asA + adv;
            ev = fmaxf(ev, 0.2f * ev);
            float p = vA ? __expf(ev) : 0.f;
            l += p;
#pragma unroll
            for (int j = 0; j < 8; ++j) acc[j] = fmaf(p, (float)hA[j], acc[j]);
        }
        {  // load A <- iter i+2
            bool nv = en < end;
            int nu = nv ? csr[en] : vc;
            hA = H8[(size_t)nu * 8 + cg];
            asA = a_s[nu * 4 + hd];
            vA = nv; en += 4;
        }
        {  // process B (iter i+1)
            float ev = asB + adv;
            ev = fmaxf(ev, 0.2f * ev);
            float p = vB ? __expf(ev) : 0.f;
            l += p;
#pragma unroll
            for (int j = 0; j < 8; ++j) acc[j] = fmaf(p, (float)hB[j], acc[j]);
        }
        {  // load B <- iter i+3
            bool nv = en < end;
            int nu = nv ? csr[en] : vc;
            hB = H8[(size_t)nu * 8 + cg];
            asB = a_s[nu * 4 + hd];
            vB = nv; en += 4;
        }
    }
    // reduce over slots (bits 3,4 of l32 -> offsets 8,16; stays in half)
#pragma unroll
    for (int off = 8; off < 32; off <<= 1) {
        l += __shfl_xor(l, off);
#pragma unroll
        for (int j = 0; j < 8; ++j) acc[j] += __shfl_xor(acc[j], off);
    }
    float rl = 1.0f / (l + 1e-16f);
    if (!FINAL) {
        if (slot == 0 && vok) {
            float o[8];
#pragma unroll
            for (int j = 0; j < 8; ++j)
                o[j] = fmaxf(fmaf(acc[j], rl, bias[8 * cg + j]), 0.f);
            float4 o0 = {o[0], o[1], o[2], o[3]};
            float4 o1 = {o[4], o[5], o[6], o[7]};
            float4* dst4 = (float4*)(out + (size_t)vc * 64 + 8 * cg);
            dst4[0] = o0;
            dst4[1] = o1;
        }
    } else {
        float p = 0.f;
#pragma unroll
        for (int j = 0; j < 8; ++j)
            p += fmaxf(fmaf(acc[j], rl, bias[8 * cg + j]), 0.f) * Wl[8 * cg + j];
        p += __shfl_xor(p, 1);
        p += __shfl_xor(p, 2);
        p += __shfl_xor(p, 4);
        if (l32 == 0 && vok) out[vc] = fmaxf(p + bl[0], 0.f);
    }
}

// ---------------- launch ----------------

extern "C" void kernel_launch(void* const* d_in, const int* in_sizes, int n_in,
                              void* d_out, int out_size, void* d_ws, size_t ws_size,
                              hipStream_t stream) {
    const float* x     = (const float*)d_in[0];
    const int*   ei    = (const int*)d_in[1];
    const float* W1    = (const float*)d_in[2];
    const float* b1    = (const float*)d_in[3];
    const float* W2    = (const float*)d_in[4];
    const float* b2    = (const float*)d_in[5];
    const float* W3    = (const float*)d_in[6];
    const float* b3    = (const float*)d_in[7];
    const float* Wg    = (const float*)d_in[8];
    const float* att_s = (const float*)d_in[9];
    const float* att_d = (const float*)d_in[10];
    const float* bg    = (const float*)d_in[11];
    const float* Wl    = (const float*)d_in[12];
    const float* bl    = (const float*)d_in[13];
    float* out = (float*)d_out;

    int n = in_sizes[0] / KIN;  // 100000
    int E = in_sizes[1] / 2;    // 1600000
    const int* srcp = ei;
    const int* dstp = ei + E;

    int NB = 512;
    int CH = (E + NB - 1) / NB;
    int NBKT = (n + 511) >> 9;
    int M = NBKT * NB;

    char* w = (char*)d_ws;
    auto alloc = [&](size_t bytes) -> void* {
        void* p = (void*)w;
        w += (bytes + 255) & ~(size_t)255;
        return p;
    };
    int*   row_ptr = (int*)alloc((size_t)(n + 1) * 4);
    int*   csr     = (int*)alloc((size_t)E * 4);
    int*   hist_g  = (int*)alloc((size_t)M * 4);
    int*   excl    = (int*)alloc((size_t)M * 4);
    int*   bsum    = (int*)alloc(512 * 4);
    int*   bpre    = (int*)alloc(512 * 4);
    float* dinv    = (float*)alloc((size_t)n * 4);
    float* a_s     = (float*)alloc((size_t)n * 4 * 4);
    float* a_d     = (float*)alloc((size_t)n * 4 * 4);
    float* bufA    = (float*)alloc((size_t)n * 64 * 4);
    float* bufB    = (float*)alloc((size_t)n * 64 * 4);
    float* bufC    = (float*)alloc((size_t)n * 64 * 4);
    int* s1 = (int*)bufB;
    int* d1 = ((int*)bufB) + E;

    int msb = (M + 255) / 256;
    rx_hist<<<NB, 256, 0, stream>>>(dstp, hist_g, E, CH, NB, NBKT);
    gs_reduce<<<msb, 256, 0, stream>>>(hist_g, bsum, M);
    gs_blocksums<<<1, 512, 0, stream>>>(bsum, bpre, msb);
    gs_scatter<<<msb, 256, 0, stream>>>(hist_g, bpre, excl, M);
    rx_scatter<<<NB, 256, 0, stream>>>(srcp, dstp, excl, s1, d1, E, CH, NB, NBKT);
    bucket_sort<<<NBKT, 512, 0, stream>>>(s1, d1, excl, csr, row_ptr, dinv, E, NB, NBKT, n);

    int waves = (n + 1) >> 1;  // 2 nodes per wave
    int agg_blocks = (waves * 64 + 255) / 256;
    int gemm_blocks = (n + 63) / 64;

    // Layer 1: GCN 128->32 (fp16 staged). H1s = dinv⊙(X@W1) -> fp16
    gemm_tile<128, 32, 64, 128, true, false, false, true><<<gemm_blocks, 128, 0, stream>>>(
        x, W1, dinv, nullptr, nullptr, nullptr, nullptr, nullptr, bufA, n);
    // agg emits G = dinv*relu(dinv*agg+b1) -> fp16
    gcn_agg_h32<1><<<agg_blocks, 256, 0, stream>>>(
        (const _Float16*)bufA, row_ptr, csr, dinv, b1, bufB, n);
    // Layer 2 agg in 32-dim (raw sum T -> f32 for the GEMM)
    gcn_agg_h32<2><<<agg_blocks, 256, 0, stream>>>(
        (const _Float16*)bufB, row_ptr, csr, nullptr, nullptr, bufA, n);
    // Fused: h2 = relu(dinv*T@W2+b2) (LDS only); A1 = h2@Wg stored FP16; attention dots
    gemm2_gat<<<gemm_blocks, 256, 0, stream>>>(bufA, W2, b2, dinv, Wg, att_s, att_d, a_s, a_d, bufB, n);
    gat_agg_h<false><<<agg_blocks, 256, 0, stream>>>(
        (const _Float16*)bufB, row_ptr, csr, a_s, a_d, bg, nullptr, nullptr, bufC, n);
    // GCN 3 + residual: gemm writes FP16, agg gathers FP16, out f32
    gemm_tile<64, 64, 64, 256, true, false, false, true><<<gemm_blocks, 256, 0, stream>>>(
        bufC, W3, dinv, nullptr, nullptr, nullptr, nullptr, nullptr, bufA, n);
    gcn_agg_h64<<<agg_blocks, 256, 0, stream>>>(
        (const _Float16*)bufA, row_ptr, csr, dinv, b3, bufC, bufB, n);
    // GAT 2 (gemm FP16-out + fused attention dots) + fused final linear
    gemm_tile<64, 64, 64, 256, false, false, true, true><<<gemm_blocks, 256, 0, stream>>>(
        bufB, Wg, nullptr, nullptr, att_s, att_d, a_s, a_d, bufA, n);
    gat_agg_h<true><<<agg_blocks, 256, 0, stream>>>(
        (const _Float16*)bufA, row_ptr, csr, a_s, a_d, bg, Wl, bl, out, n);
}

// Round 10
// 428.594 us; speedup vs baseline: 1.0296x; 1.0296x over previous
//
#include <hip/hip_runtime.h>
#include <math.h>

constexpr int KIN = 128;   // IN_F

typedef _Float16 half8_t __attribute__((ext_vector_type(8)));
typedef _Float16 half4_t __attribute__((ext_vector_type(4)));

// ---------------- graph build: MSD bucket sort (dst>>9), then per-bucket
// counting sort by dst&511. NB=512 chunks (rx_* were occupancy-starved at 128). --

__global__ void rx_hist(const int* __restrict__ dst, int* __restrict__ hist_g,
                        int E, int CH, int NB, int NBKT) {
    __shared__ int h[256];
    int b = blockIdx.x;
    for (int i = threadIdx.x; i < 256; i += blockDim.x) h[i] = 0;
    __syncthreads();
    int beg = b * CH, end = min(beg + CH, E);
    for (int e = beg + threadIdx.x; e < end; e += blockDim.x)
        atomicAdd(&h[dst[e] >> 9], 1);
    __syncthreads();
    for (int d = threadIdx.x; d < NBKT; d += blockDim.x)
        hist_g[d * NB + b] = h[d];
}

__global__ void gs_reduce(const int* __restrict__ a, int* __restrict__ bsum, int m) {
    __shared__ int s[256];
    int t = threadIdx.x;
    int i = blockIdx.x * 256 + t;
    s[t] = (i < m) ? a[i] : 0;
    __syncthreads();
    for (int off = 128; off > 0; off >>= 1) {
        if (t < off) s[t] += s[t + off];
        __syncthreads();
    }
    if (t == 0) bsum[blockIdx.x] = s[0];
}

__global__ void gs_blocksums(const int* __restrict__ bsum, int* __restrict__ bpre, int nb) {
    __shared__ int s[512];
    int t = threadIdx.x;
    int val = (t < nb) ? bsum[t] : 0;
    s[t] = val;
    __syncthreads();
    for (int off = 1; off < 512; off <<= 1) {
        int x = (t >= off) ? s[t - off] : 0;
        __syncthreads();
        s[t] += x;
        __syncthreads();
    }
    if (t < nb) bpre[t] = s[t] - val;  // exclusive
}

__global__ void gs_scatter(const int* __restrict__ a, const int* __restrict__ bpre,
                           int* __restrict__ out, int m) {
    __shared__ int s[256];
    int t = threadIdx.x;
    int i = blockIdx.x * 256 + t;
    int val = (i < m) ? a[i] : 0;
    s[t] = val;
    __syncthreads();
    for (int off = 1; off < 256; off <<= 1) {
        int x = (t >= off) ? s[t - off] : 0;
        __syncthreads();
        s[t] += x;
        __syncthreads();
    }
    if (i < m) out[i] = bpre[blockIdx.x] + s[t] - val;
}

__global__ void rx_scatter(const int* __restrict__ src, const int* __restrict__ dst,
                           const int* __restrict__ excl, int* __restrict__ s1,
                           int* __restrict__ d1, int E, int CH, int NB, int NBKT) {
    __shared__ int offs[256];
    int b = blockIdx.x;
    for (int d = threadIdx.x; d < NBKT; d += blockDim.x)
        offs[d] = excl[d * NB + b];
    __syncthreads();
    int beg = b * CH, end = min(beg + CH, E);
    for (int e = beg + threadIdx.x; e < end; e += blockDim.x) {
        int dd = dst[e];
        int pos = atomicAdd(&offs[dd >> 9], 1);
        s1[pos] = src[e];
        d1[pos] = dd;
    }
}

__global__ void __launch_bounds__(512)
bucket_sort(const int* __restrict__ s1, const int* __restrict__ d1,
            const int* __restrict__ excl, int* __restrict__ csr,
            int* __restrict__ row_ptr, float* __restrict__ dinv,
            int E, int NB, int NBKT, int n) {
    __shared__ int hist[512];
    __shared__ int scan[512];
    __shared__ int offs[512];
    int b = blockIdx.x, t = threadIdx.x;
    int base = excl[b * NB];
    int endb = (b + 1 < NBKT) ? excl[(b + 1) * NB] : E;
    hist[t] = 0;
    __syncthreads();
    for (int i = base + t; i < endb; i += 512)
        atomicAdd(&hist[d1[i] & 511], 1);
    __syncthreads();
    int v = hist[t];
    scan[t] = v;
    __syncthreads();
    for (int off = 1; off < 512; off <<= 1) {
        int x = (t >= off) ? scan[t - off] : 0;
        __syncthreads();
        scan[t] += x;
        __syncthreads();
    }
    int ex = scan[t] - v;  // exclusive prefix within bucket
    offs[t] = ex;
    int node = b * 512 + t;
    if (node < n) {
        row_ptr[node] = base + ex;
        dinv[node] = 1.0f / sqrtf((float)(v + 1));  // +1 self loop
    }
    if (b == NBKT - 1 && t == 0) row_ptr[n] = E;
    __syncthreads();
    for (int i = base + t; i < endb; i += 512) {
        int dd = d1[i];
        int pos = atomicAdd(&offs[dd & 511], 1);
        csr[base + pos] = s1[i];
    }
}

// ---------------- tiled register-blocked GEMM ----------------
template <int K, int F, int BM, int THREADS, bool SCALE, bool BRELU, bool ATT, bool OUT16>
__global__ void __launch_bounds__(THREADS)
gemm_tile(const float* __restrict__ in, const float* __restrict__ W,
          const float* __restrict__ dinv, const float* __restrict__ bias,
          const float* __restrict__ att_src, const float* __restrict__ att_dst,
          float* __restrict__ a_s, float* __restrict__ a_d,
          float* __restrict__ out, int n) {
    constexpr int TM = 4, TN = 4;
    constexpr int TX = F / TN;
    constexpr int TY = BM / TM;
    static_assert(THREADS == TX * TY, "thread count mismatch");
    constexpr int K4 = K / 4;
    __shared__ float xs[K][BM];
    __shared__ float Ws[K * F];
    int t = threadIdx.x;
    int row0 = blockIdx.x * BM;

    for (int i = t; i < K * F / 4; i += THREADS)
        ((float4*)Ws)[i] = ((const float4*)W)[i];

    for (int i = t; i < BM * K4; i += THREADS) {
        int r = i % BM, k4 = i / BM;
        int row = row0 + r;
        float4 v = {0.f, 0.f, 0.f, 0.f};
        if (row < n) v = ((const float4*)(in + (size_t)row * K))[k4];
        xs[4 * k4 + 0][r] = v.x;
        xs[4 * k4 + 1][r] = v.y;
        xs[4 * k4 + 2][r] = v.z;
        xs[4 * k4 + 3][r] = v.w;
    }
    __syncthreads();

    int tx = t % TX, ty = t / TX;
    float acc[TM][TN] = {};
#pragma unroll 4
    for (int k = 0; k < K; ++k) {
        float4 xv = *(const float4*)&xs[k][ty * TM];
        float4 wv = *(const float4*)&Ws[k * F + tx * TN];
        float xr[4] = {xv.x, xv.y, xv.z, xv.w};
        float wr[4] = {wv.x, wv.y, wv.z, wv.w};
#pragma unroll
        for (int i = 0; i < TM; ++i)
#pragma unroll
            for (int j = 0; j < TN; ++j)
                acc[i][j] = fmaf(xr[i], wr[j], acc[i][j]);
    }

#pragma unroll
    for (int i = 0; i < TM; ++i) {
        int row = row0 + ty * TM + i;
        if (row >= n) continue;
        float s = SCALE ? dinv[row] : 1.0f;
        float o[4];
        if (BRELU) {
            o[0] = fmaxf(fmaf(acc[i][0], s, bias[4 * tx + 0]), 0.f);
            o[1] = fmaxf(fmaf(acc[i][1], s, bias[4 * tx + 1]), 0.f);
            o[2] = fmaxf(fmaf(acc[i][2], s, bias[4 * tx + 2]), 0.f);
            o[3] = fmaxf(fmaf(acc[i][3], s, bias[4 * tx + 3]), 0.f);
        } else {
            o[0] = acc[i][0] * s; o[1] = acc[i][1] * s;
            o[2] = acc[i][2] * s; o[3] = acc[i][3] * s;
        }
        if (OUT16) {
            half4_t oh;
            oh[0] = (_Float16)o[0]; oh[1] = (_Float16)o[1];
            oh[2] = (_Float16)o[2]; oh[3] = (_Float16)o[3];
            *(half4_t*)((_Float16*)out + (size_t)row * F + 4 * tx) = oh;
        } else {
            float4 of = {o[0], o[1], o[2], o[3]};
            ((float4*)(out + (size_t)row * F))[tx] = of;
        }
    }
    if (ATT) {
        int hd = tx >> 2;
        float as0 = att_src[4 * tx + 0], as1 = att_src[4 * tx + 1];
        float as2 = att_src[4 * tx + 2], as3 = att_src[4 * tx + 3];
        float ad0 = att_dst[4 * tx + 0], ad1 = att_dst[4 * tx + 1];
        float ad2 = att_dst[4 * tx + 2], ad3 = att_dst[4 * tx + 3];
#pragma unroll
        for (int i = 0; i < TM; ++i) {
            float ps = acc[i][0] * as0 + acc[i][1] * as1 + acc[i][2] * as2 + acc[i][3] * as3;
            float pd = acc[i][0] * ad0 + acc[i][1] * ad1 + acc[i][2] * ad2 + acc[i][3] * ad3;
            ps += __shfl_xor(ps, 1); pd += __shfl_xor(pd, 1);
            ps += __shfl_xor(ps, 2); pd += __shfl_xor(pd, 2);
            int row = row0 + ty * TM + i;
            if ((tx & 3) == 0 && row < n) {
                a_s[row * 4 + hd] = ps;
                a_d[row * 4 + hd] = pd;
            }
        }
    }
}

// ---------------- fused layer2-GEMM + GAT1-GEMM (A1 stored fp16) ----------------
__global__ void __launch_bounds__(256)
gemm2_gat(const float* __restrict__ T, const float* __restrict__ W2,
          const float* __restrict__ b2, const float* __restrict__ dinv,
          const float* __restrict__ Wg, const float* __restrict__ att_src,
          const float* __restrict__ att_dst, float* __restrict__ a_s,
          float* __restrict__ a_d, float* __restrict__ A1, int n) {
    __shared__ float xs[32][64];
    __shared__ float W2s[32 * 64];
    __shared__ float Wgs[64 * 64];
    __shared__ float hs[64][68];
    int t = threadIdx.x;
    int row0 = blockIdx.x * 64;

    for (int i = t; i < 32 * 64 / 4; i += 256) ((float4*)W2s)[i] = ((const float4*)W2)[i];
    for (int i = t; i < 64 * 64 / 4; i += 256) ((float4*)Wgs)[i] = ((const float4*)Wg)[i];
    for (int i = t; i < 64 * 8; i += 256) {
        int r = i % 64, k4 = i / 64;
        int row = row0 + r;
        float4 v = {0.f, 0.f, 0.f, 0.f};
        if (row < n) v = ((const float4*)(T + (size_t)row * 32))[k4];
        xs[4 * k4 + 0][r] = v.x;
        xs[4 * k4 + 1][r] = v.y;
        xs[4 * k4 + 2][r] = v.z;
        xs[4 * k4 + 3][r] = v.w;
    }
    __syncthreads();

    int tx = t % 16, ty = t / 16;
    {
        float acc[4][4] = {};
#pragma unroll 4
        for (int k = 0; k < 32; ++k) {
            float4 xv = *(const float4*)&xs[k][ty * 4];
            float4 wv = *(const float4*)&W2s[k * 64 + tx * 4];
            float xr[4] = {xv.x, xv.y, xv.z, xv.w};
            float wr[4] = {wv.x, wv.y, wv.z, wv.w};
#pragma unroll
            for (int i = 0; i < 4; ++i)
#pragma unroll
                for (int j = 0; j < 4; ++j)
                    acc[i][j] = fmaf(xr[i], wr[j], acc[i][j]);
        }
#pragma unroll
        for (int i = 0; i < 4; ++i) {
            int row = row0 + ty * 4 + i;
            float s = (row < n) ? dinv[row] : 0.f;
#pragma unroll
            for (int j = 0; j < 4; ++j)
                hs[4 * tx + j][ty * 4 + i] = fmaxf(fmaf(acc[i][j], s, b2[4 * tx + j]), 0.f);
        }
    }
    __syncthreads();

    float acc[4][4] = {};
#pragma unroll 4
    for (int k = 0; k < 64; ++k) {
        float4 xv = *(const float4*)&hs[k][ty * 4];
        float4 wv = *(const float4*)&Wgs[k * 64 + tx * 4];
        float xr[4] = {xv.x, xv.y, xv.z, xv.w};
        float wr[4] = {wv.x, wv.y, wv.z, wv.w};
#pragma unroll
        for (int i = 0; i < 4; ++i)
#pragma unroll
            for (int j = 0; j < 4; ++j)
                acc[i][j] = fmaf(xr[i], wr[j], acc[i][j]);
    }
    _Float16* A1h = (_Float16*)A1;
#pragma unroll
    for (int i = 0; i < 4; ++i) {
        int row = row0 + ty * 4 + i;
        if (row >= n) continue;
        half4_t oh;
        oh[0] = (_Float16)acc[i][0]; oh[1] = (_Float16)acc[i][1];
        oh[2] = (_Float16)acc[i][2]; oh[3] = (_Float16)acc[i][3];
        *(half4_t*)(A1h + (size_t)row * 64 + 4 * tx) = oh;
    }
    {
        int hd = tx >> 2;
        float as0 = att_src[4 * tx + 0], as1 = att_src[4 * tx + 1];
        float as2 = att_src[4 * tx + 2], as3 = att_src[4 * tx + 3];
        float ad0 = att_dst[4 * tx + 0], ad1 = att_dst[4 * tx + 1];
        float ad2 = att_dst[4 * tx + 2], ad3 = att_dst[4 * tx + 3];
#pragma unroll
        for (int i = 0; i < 4; ++i) {
            float ps = acc[i][0] * as0 + acc[i][1] * as1 + acc[i][2] * as2 + acc[i][3] * as3;
            float pd = acc[i][0] * ad0 + acc[i][1] * ad1 + acc[i][2] * ad2 + acc[i][3] * ad3;
            ps += __shfl_xor(ps, 1); pd += __shfl_xor(pd, 1);
            ps += __shfl_xor(ps, 2); pd += __shfl_xor(pd, 2);
            int row = row0 + ty * 4 + i;
            if ((tx & 3) == 0 && row < n) {
                a_s[row * 4 + hd] = ps;
                a_d[row * 4 + hd] = pd;
            }
        }
    }
}

// ---------------- aggregation kernels: 2 nodes/wave, batch-N gather ----------
// Per loop body: load ALL csr indices for the batch first (independent, same
// cache line per half), then issue ALL H-row / a_s gathers back-to-back
// (4 independent gathers in flight per slot-group vs 1 in the rolling scheme),
// then process. Converts the csr->H dependent chain into real gather MLP.

// fp16-gather GCN agg, 32-wide rows (64B). Per half: 4 cg-lanes x 8 slots, batch-2.
// MODE 1: out[fp16] = dinv*relu(dinv*acc + b)   MODE 2: out[f32] = acc
template <int MODE>
__global__ void __launch_bounds__(256)
gcn_agg_h32(const _Float16* __restrict__ Hs, const int* __restrict__ row_ptr,
            const int* __restrict__ csr, const float* __restrict__ dinv,
            const float* __restrict__ bias, void* __restrict__ outp, int n) {
    int idx = blockIdx.x * blockDim.x + threadIdx.x;
    int wave = idx >> 6;
    int lane = idx & 63;
    int half = lane >> 5;
    int l32 = lane & 31;
    int v = (wave << 1) + half;
    bool vok = v < n;
    int vc = vok ? v : 0;
    int cg = l32 & 3;     // 8 halves per lane
    int slot = l32 >> 2;  // 8 edge slots
    const half8_t* H8 = (const half8_t*)Hs;  // row stride = 4 half8

    float acc[8] = {};
    if (slot == 0 && vok) {  // self loop
        half8_t h = H8[(size_t)vc * 4 + cg];
#pragma unroll
        for (int j = 0; j < 8; ++j) acc[j] = (float)h[j];
    }
    int beg = row_ptr[vc];
    int end = vok ? row_ptr[vc + 1] : beg;
    for (int base = beg; base < end; base += 16) {
        int e0 = base + slot, e1 = e0 + 8;
        bool v0 = e0 < end, v1 = e1 < end;
        int u0 = v0 ? csr[e0] : vc;
        int u1 = v1 ? csr[e1] : vc;
        half8_t h0 = H8[(size_t)u0 * 4 + cg];
        half8_t h1 = H8[(size_t)u1 * 4 + cg];
        float m0 = v0 ? 1.f : 0.f;
#pragma unroll
        for (int j = 0; j < 8; ++j) acc[j] = fmaf(m0, (float)h0[j], acc[j]);
        float m1 = v1 ? 1.f : 0.f;
#pragma unroll
        for (int j = 0; j < 8; ++j) acc[j] = fmaf(m1, (float)h1[j], acc[j]);
    }
    // reduce over slots (bits 2,3,4 of l32 -> offsets 4,8,16; stays in half)
#pragma unroll
    for (int off = 4; off < 32; off <<= 1) {
#pragma unroll
        for (int j = 0; j < 8; ++j) acc[j] += __shfl_xor(acc[j], off);
    }
    if (slot == 0 && vok) {
        if (MODE == 1) {
            float dv = dinv[vc];
            half8_t o;
#pragma unroll
            for (int j = 0; j < 8; ++j)
                o[j] = (_Float16)(dv * fmaxf(fmaf(dv, acc[j], bias[8 * cg + j]), 0.f));
            ((half8_t*)outp)[(size_t)vc * 4 + cg] = o;
        } else {
            float* of = (float*)outp;
            float4 o0 = {acc[0], acc[1], acc[2], acc[3]};
            float4 o1 = {acc[4], acc[5], acc[6], acc[7]};
            float4* dst4 = (float4*)(of + (size_t)vc * 32 + 8 * cg);
            dst4[0] = o0;
            dst4[1] = o1;
        }
    }
}

// fp16-gather GCN agg, F=64, relu+bias+residual, f32 out. Per half: 8 cg x 4 slots,
// batch-4 (covers 16 edges per body; typical node = one body).
__global__ void __launch_bounds__(256)
gcn_agg_h64(const _Float16* __restrict__ Hs, const int* __restrict__ row_ptr,
            const int* __restrict__ csr, const float* __restrict__ dinv,
            const float* __restrict__ bias, const float* __restrict__ res,
            float* __restrict__ out, int n) {
    int idx = blockIdx.x * blockDim.x + threadIdx.x;
    int wave = idx >> 6;
    int lane = idx & 63;
    int half = lane >> 5;
    int l32 = lane & 31;
    int v = (wave << 1) + half;
    bool vok = v < n;
    int vc = vok ? v : 0;
    int cg = l32 & 7;     // 8 halves per lane
    int slot = l32 >> 3;  // 4 edge slots
    const half8_t* H8 = (const half8_t*)Hs;

    float acc[8] = {};
    if (slot == 0 && vok) {  // self loop
        half8_t h = H8[(size_t)vc * 8 + cg];
#pragma unroll
        for (int j = 0; j < 8; ++j) acc[j] = (float)h[j];
    }
    int beg = row_ptr[vc];
    int end = vok ? row_ptr[vc + 1] : beg;
    for (int base = beg; base < end; base += 16) {
        int e0 = base + slot, e1 = e0 + 4, e2 = e0 + 8, e3 = e0 + 12;
        bool v0 = e0 < end, v1 = e1 < end, v2 = e2 < end, v3 = e3 < end;
        int u0 = v0 ? csr[e0] : vc;
        int u1 = v1 ? csr[e1] : vc;
        int u2 = v2 ? csr[e2] : vc;
        int u3 = v3 ? csr[e3] : vc;
        half8_t h0 = H8[(size_t)u0 * 8 + cg];
        half8_t h1 = H8[(size_t)u1 * 8 + cg];
        half8_t h2 = H8[(size_t)u2 * 8 + cg];
        half8_t h3 = H8[(size_t)u3 * 8 + cg];
        float m0 = v0 ? 1.f : 0.f;
#pragma unroll
        for (int j = 0; j < 8; ++j) acc[j] = fmaf(m0, (float)h0[j], acc[j]);
        float m1 = v1 ? 1.f : 0.f;
#pragma unroll
        for (int j = 0; j < 8; ++j) acc[j] = fmaf(m1, (float)h1[j], acc[j]);
        float m2 = v2 ? 1.f : 0.f;
#pragma unroll
        for (int j = 0; j < 8; ++j) acc[j] = fmaf(m2, (float)h2[j], acc[j]);
        float m3 = v3 ? 1.f : 0.f;
#pragma unroll
        for (int j = 0; j < 8; ++j) acc[j] = fmaf(m3, (float)h3[j], acc[j]);
    }
    // reduce over slots (bits 3,4 of l32 -> offsets 8,16; stays in half)
#pragma unroll
    for (int off = 8; off < 32; off <<= 1) {
#pragma unroll
        for (int j = 0; j < 8; ++j) acc[j] += __shfl_xor(acc[j], off);
    }
    if (slot == 0 && vok) {
        float dv = dinv[vc];
        const float4* r4 = (const float4*)(res + (size_t)vc * 64 + 8 * cg);
        float4 r0 = r4[0], r1 = r4[1];
        float o[8];
#pragma unroll
        for (int j = 0; j < 8; ++j)
            o[j] = fmaxf(fmaf(dv, acc[j], bias[8 * cg + j]), 0.f);
        float4 o0 = {o[0] + r0.x, o[1] + r0.y, o[2] + r0.z, o[3] + r0.w};
        float4 o1 = {o[4] + r1.x, o[5] + r1.y, o[6] + r1.z, o[7] + r1.w};
        float4* dst4 = (float4*)(out + (size_t)vc * 64 + 8 * cg);
        dst4[0] = o0;
        dst4[1] = o1;
    }
}

// fp16-gather GAT agg. Per half: 8 cg-lanes x 4 slots, batch-4 gather.
template <bool FINAL>
__global__ void __launch_bounds__(256)
gat_agg_h(const _Float16* __restrict__ H, const int* __restrict__ row_ptr,
          const int* __restrict__ csr, const float* __restrict__ a_s,
          const float* __restrict__ a_d, const float* __restrict__ bias,
          const float* __restrict__ Wl, const float* __restrict__ bl,
          float* __restrict__ out, int n) {
    int idx = blockIdx.x * blockDim.x + threadIdx.x;
    int wave = idx >> 6;
    int lane = idx & 63;
    int half = lane >> 5;
    int l32 = lane & 31;
    int v = (wave << 1) + half;
    bool vok = v < n;
    int vc = vok ? v : 0;
    int cg = l32 & 7;     // 8 halves (one head-half) per lane
    int slot = l32 >> 3;  // 4 edge slots
    int hd = cg >> 1;
    const half8_t* H8 = (const half8_t*)H;

    float adv = a_d[vc * 4 + hd];
    float l = 0.f;
    float acc[8] = {};
    if (slot == 0 && vok) {  // self edge
        float e0s = a_s[vc * 4 + hd] + adv;
        e0s = fmaxf(e0s, 0.2f * e0s);
        float p = __expf(e0s);
        l = p;
        half8_t h = H8[(size_t)vc * 8 + cg];
#pragma unroll
        for (int j = 0; j < 8; ++j) acc[j] = p * (float)h[j];
    }
    int beg = row_ptr[vc];
    int end = vok ? row_ptr[vc + 1] : beg;
    for (int base = beg; base < end; base += 16) {
        int e0 = base + slot, e1 = e0 + 4, e2 = e0 + 8, e3 = e0 + 12;
        bool v0 = e0 < end, v1 = e1 < end, v2 = e2 < end, v3 = e3 < end;
        int u0 = v0 ? csr[e0] : vc;
        int u1 = v1 ? csr[e1] : vc;
        int u2 = v2 ? csr[e2] : vc;
        int u3 = v3 ? csr[e3] : vc;
        half8_t h0 = H8[(size_t)u0 * 8 + cg];
        half8_t h1 = H8[(size_t)u1 * 8 + cg];
        half8_t h2 = H8[(size_t)u2 * 8 + cg];
        half8_t h3 = H8[(size_t)u3 * 8 + cg];
        float as0 = a_s[u0 * 4 + hd];
        float as1 = a_s[u1 * 4 + hd];
        float as2 = a_s[u2 * 4 + hd];
        float as3 = a_s[u3 * 4 + hd];
        {
            float ev = as0 + adv;
            ev = fmaxf(ev, 0.2f * ev);
            float p = v0 ? __expf(ev) : 0.f;
            l += p;
#pragma unroll
            for (int j = 0; j < 8; ++j) acc[j] = fmaf(p, (float)h0[j], acc[j]);
        }
        {
            float ev = as1 + adv;
            ev = fmaxf(ev, 0.2f * ev);
            float p = v1 ? __expf(ev) : 0.f;
            l += p;
#pragma unroll
            for (int j = 0; j < 8; ++j) acc[j] = fmaf(p, (float)h1[j], acc[j]);
        }
        {
            float ev = as2 + adv;
            ev = fmaxf(ev, 0.2f * ev);
            float p = v2 ? __expf(ev) : 0.f;
            l += p;
#pragma unroll
            for (int j = 0; j < 8; ++j) acc[j] = fmaf(p, (float)h2[j], acc[j]);
        }
        {
            float ev = as3 + adv;
            ev = fmaxf(ev, 0.2f * ev);
            float p = v3 ? __expf(ev) : 0.f;
            l += p;
#pragma unroll
            for (int j = 0; j < 8; ++j) acc[j] = fmaf(p, (float)h3[j], acc[j]);
        }
    }
    // reduce over slots (bits 3,4 of l32 -> offsets 8,16; stays in half)
#pragma unroll
    for (int off = 8; off < 32; off <<= 1) {
        l += __shfl_xor(l, off);
#pragma unroll
        for (int j = 0; j < 8; ++j) acc[j] += __shfl_xor(acc[j], off);
    }
    float rl = 1.0f / (l + 1e-16f);
    if (!FINAL) {
        if (slot == 0 && vok) {
            float o[8];
#pragma unroll
            for (int j = 0; j < 8; ++j)
                o[j] = fmaxf(fmaf(acc[j], rl, bias[8 * cg + j]), 0.f);
            float4 o0 = {o[0], o[1], o[2], o[3]};
            float4 o1 = {o[4], o[5], o[6], o[7]};
            float4* dst4 = (float4*)(out + (size_t)vc * 64 + 8 * cg);
            dst4[0] = o0;
            dst4[1] = o1;
        }
    } else {
        float p = 0.f;
#pragma unroll
        for (int j = 0; j < 8; ++j)
            p += fmaxf(fmaf(acc[j], rl, bias[8 * cg + j]), 0.f) * Wl[8 * cg + j];
        p += __shfl_xor(p, 1);
        p += __shfl_xor(p, 2);
        p += __shfl_xor(p, 4);
        if (l32 == 0 && vok) out[vc] = fmaxf(p + bl[0], 0.f);
    }
}

// ---------------- launch ----------------

extern "C" void kernel_launch(void* const* d_in, const int* in_sizes, int n_in,
                              void* d_out, int out_size, void* d_ws, size_t ws_size,
                              hipStream_t stream) {
    const float* x     = (const float*)d_in[0];
    const int*   ei    = (const int*)d_in[1];
    const float* W1    = (const float*)d_in[2];
    const float* b1    = (const float*)d_in[3];
    const float* W2    = (const float*)d_in[4];
    const float* b2    = (const float*)d_in[5];
    const float* W3    = (const float*)d_in[6];
    const float* b3    = (const float*)d_in[7];
    const float* Wg    = (const float*)d_in[8];
    const float* att_s = (const float*)d_in[9];
    const float* att_d = (const float*)d_in[10];
    const float* bg    = (const float*)d_in[11];
    const float* Wl    = (const float*)d_in[12];
    const float* bl    = (const float*)d_in[13];
    float* out = (float*)d_out;

    int n = in_sizes[0] / KIN;  // 100000
    int E = in_sizes[1] / 2;    // 1600000
    const int* srcp = ei;
    const int* dstp = ei + E;

    int NB = 512;
    int CH = (E + NB - 1) / NB;
    int NBKT = (n + 511) >> 9;
    int M = NBKT * NB;

    char* w = (char*)d_ws;
    auto alloc = [&](size_t bytes) -> void* {
        void* p = (void*)w;
        w += (bytes + 255) & ~(size_t)255;
        return p;
    };
    int*   row_ptr = (int*)alloc((size_t)(n + 1) * 4);
    int*   csr     = (int*)alloc((size_t)E * 4);
    int*   hist_g  = (int*)alloc((size_t)M * 4);
    int*   excl    = (int*)alloc((size_t)M * 4);
    int*   bsum    = (int*)alloc(512 * 4);
    int*   bpre    = (int*)alloc(512 * 4);
    float* dinv    = (float*)alloc((size_t)n * 4);
    float* a_s     = (float*)alloc((size_t)n * 4 * 4);
    float* a_d     = (float*)alloc((size_t)n * 4 * 4);
    float* bufA    = (float*)alloc((size_t)n * 64 * 4);
    float* bufB    = (float*)alloc((size_t)n * 64 * 4);
    float* bufC    = (float*)alloc((size_t)n * 64 * 4);
    int* s1 = (int*)bufB;
    int* d1 = ((int*)bufB) + E;

    int msb = (M + 255) / 256;
    rx_hist<<<NB, 256, 0, stream>>>(dstp, hist_g, E, CH, NB, NBKT);
    gs_reduce<<<msb, 256, 0, stream>>>(hist_g, bsum, M);
    gs_blocksums<<<1, 512, 0, stream>>>(bsum, bpre, msb);
    gs_scatter<<<msb, 256, 0, stream>>>(hist_g, bpre, excl, M);
    rx_scatter<<<NB, 256, 0, stream>>>(srcp, dstp, excl, s1, d1, E, CH, NB, NBKT);
    bucket_sort<<<NBKT, 512, 0, stream>>>(s1, d1, excl, csr, row_ptr, dinv, E, NB, NBKT, n);

    int waves = (n + 1) >> 1;  // 2 nodes per wave
    int agg_blocks = (waves * 64 + 255) / 256;
    int gemm_blocks = (n + 63) / 64;

    // Layer 1: GCN 128->32 (fp16 staged). H1s = dinv⊙(X@W1) -> fp16
    gemm_tile<128, 32, 64, 128, true, false, false, true><<<gemm_blocks, 128, 0, stream>>>(
        x, W1, dinv, nullptr, nullptr, nullptr, nullptr, nullptr, bufA, n);
    // agg emits G = dinv*relu(dinv*agg+b1) -> fp16
    gcn_agg_h32<1><<<agg_blocks, 256, 0, stream>>>(
        (const _Float16*)bufA, row_ptr, csr, dinv, b1, bufB, n);
    // Layer 2 agg in 32-dim (raw sum T -> f32 for the GEMM)
    gcn_agg_h32<2><<<agg_blocks, 256, 0, stream>>>(
        (const _Float16*)bufB, row_ptr, csr, nullptr, nullptr, bufA, n);
    // Fused: h2 = relu(dinv*T@W2+b2) (LDS only); A1 = h2@Wg stored FP16; attention dots
    gemm2_gat<<<gemm_blocks, 256, 0, stream>>>(bufA, W2, b2, dinv, Wg, att_s, att_d, a_s, a_d, bufB, n);
    gat_agg_h<false><<<agg_blocks, 256, 0, stream>>>(
        (const _Float16*)bufB, row_ptr, csr, a_s, a_d, bg, nullptr, nullptr, bufC, n);
    // GCN 3 + residual: gemm writes FP16, agg gathers FP16, out f32
    gemm_tile<64, 64, 64, 256, true, false, false, true><<<gemm_blocks, 256, 0, stream>>>(
        bufC, W3, dinv, nullptr, nullptr, nullptr, nullptr, nullptr, bufA, n);
    gcn_agg_h64<<<agg_blocks, 256, 0, stream>>>(
        (const _Float16*)bufA, row_ptr, csr, dinv, b3, bufC, bufB, n);
    // GAT 2 (gemm FP16-out + fused attention dots) + fused final linear
    gemm_tile<64, 64, 64, 256, false, false, true, true><<<gemm_blocks, 256, 0, stream>>>(
        bufB, Wg, nullptr, nullptr, att_s, att_d, a_s, a_d, bufA, n);
    gat_agg_h<true><<<agg_blocks, 256, 0, stream>>>(
        (const _Float16*)bufA, row_ptr, csr, a_s, a_d, bg, Wl, bl, out, n);
}